// Round 1
// baseline (3254.864 us; speedup 1.0000x reference)
//
#include <hip/hip_runtime.h>
#include <math.h>

// ---------------------------------------------------------------------------
// JKNet: 2-layer GCN (sym-norm A+I) + sum-JK + linear + log_softmax
// All fp32. Self-loop contribution handled analytically (h[i]*dis[i]^2) in the
// bias/relu pass instead of via atomics.
// ---------------------------------------------------------------------------

__global__ void set_ones(float* __restrict__ p, int n) {
    int i = blockIdx.x * blockDim.x + threadIdx.x;
    if (i < n) p[i] = 1.0f;
}

__global__ void deg_count(const int* __restrict__ dst, float* __restrict__ deg, int E) {
    int e = blockIdx.x * blockDim.x + threadIdx.x;
    if (e < E) atomicAdd(&deg[dst[e]], 1.0f);
}

__global__ void to_rsqrt(float* __restrict__ p, int n) {
    int i = blockIdx.x * blockDim.x + threadIdx.x;
    if (i < n) p[i] = rsqrtf(p[i]);
}

// H[n,128] = X[n,K] @ W[K,128].  Block = 256 threads, 64 rows per block.
// W staged through LDS in 128-row K-tiles (64 KB -> 2 blocks/CU).
__global__ void gemm128(const float* __restrict__ X, const float* __restrict__ W,
                        float* __restrict__ H, int n, int K) {
    __shared__ float ws[128][128];
    int tid  = threadIdx.x;
    int col  = tid & 127;
    int rh   = tid >> 7;          // 0 or 1
    int row0 = blockIdx.x * 64;
    float acc[32];
#pragma unroll
    for (int i = 0; i < 32; i++) acc[i] = 0.f;

    for (int kt = 0; kt < K; kt += 128) {
        __syncthreads();
        for (int i = tid; i < 128 * 128; i += 256)
            ws[i >> 7][i & 127] = W[(size_t)(kt + (i >> 7)) * 128 + (i & 127)];
        __syncthreads();
        for (int rp = 0; rp < 32; rp++) {
            int r = row0 + rp * 2 + rh;
            if (r < n) {
                const float* xr = X + (size_t)r * K + kt;
                float a = acc[rp];
#pragma unroll 4
                for (int k = 0; k < 128; k++) a = fmaf(xr[k], ws[k][col], a);
                acc[rp] = a;
            }
        }
    }
    for (int rp = 0; rp < 32; rp++) {
        int r = row0 + rp * 2 + rh;
        if (r < n) H[(size_t)r * 128 + col] = acc[rp];
    }
}

// agg[dst] += h[src] * dis[src]*dis[dst], 128 features/edge (2 waves/edge).
__global__ void scatter(const float* __restrict__ H, const int* __restrict__ src,
                        const int* __restrict__ dst, const float* __restrict__ dis,
                        float* __restrict__ agg, int E) {
    long long idx = (long long)blockIdx.x * 256 + threadIdx.x;
    int e = (int)(idx >> 7);
    int f = (int)(idx & 127);
    if (e >= E) return;
    int s = src[e], d = dst[e];
    float nrm = dis[s] * dis[d];
    atomicAdd(&agg[(size_t)d * 128 + f], H[(size_t)s * 128 + f] * nrm);
}

// agg = relu(agg + H*dis^2 + b)   (adds the self-loop message + bias)
__global__ void bias_relu_self(float* __restrict__ agg, const float* __restrict__ H,
                               const float* __restrict__ dis, const float* __restrict__ b,
                               int n) {
    long long idx = (long long)blockIdx.x * 256 + threadIdx.x;
    if (idx >= (long long)n * 128) return;
    int i = (int)(idx >> 7), f = (int)(idx & 127);
    float di = dis[i];
    float v  = agg[idx] + H[idx] * di * di + b[f];
    agg[idx] = v > 0.f ? v : 0.f;
}

// out[node, 0:41] = log_softmax((x1+x2) @ lw + lb). One wave per node.
__global__ void final_k(const float* __restrict__ x1, const float* __restrict__ x2,
                        const float* __restrict__ lw, const float* __restrict__ lb,
                        float* __restrict__ out, int n) {
    __shared__ float s[4][128];
    int g    = threadIdx.x >> 6;
    int lane = threadIdx.x & 63;
    int node = blockIdx.x * 4 + g;
    if (node < n) {
        size_t base = (size_t)node * 128;
        s[g][lane]      = x1[base + lane]      + x2[base + lane];
        s[g][lane + 64] = x1[base + lane + 64] + x2[base + lane + 64];
    }
    __syncthreads();

    bool active = (node < n) && (lane < 41);
    float val = 0.f;
    if (active) {
#pragma unroll 4
        for (int f = 0; f < 128; f++) val = fmaf(s[g][f], lw[f * 41 + lane], val);
        val += lb[lane];
    }
    float m = active ? val : -INFINITY;
#pragma unroll
    for (int off = 32; off > 0; off >>= 1) m = fmaxf(m, __shfl_xor(m, off, 64));
    float e = active ? expf(val - m) : 0.f;
#pragma unroll
    for (int off = 32; off > 0; off >>= 1) e += __shfl_xor(e, off, 64);
    if (active) out[(size_t)node * 41 + lane] = val - m - logf(e);
}

extern "C" void kernel_launch(void* const* d_in, const int* in_sizes, int n_in,
                              void* d_out, int out_size, void* d_ws, size_t ws_size,
                              hipStream_t stream) {
    const float* x  = (const float*)d_in[0];
    const int*   ei = (const int*)d_in[1];
    const float* W1 = (const float*)d_in[2];
    const float* b1 = (const float*)d_in[3];
    const float* W2 = (const float*)d_in[4];
    const float* b2 = (const float*)d_in[5];
    const float* lw = (const float*)d_in[6];
    const float* lb = (const float*)d_in[7];
    float* out = (float*)d_out;

    const int n = in_sizes[0] / 256;   // 100000
    const int E = in_sizes[1] / 2;     // 1.6M
    const int* src = ei;
    const int* dst = ei + E;

    float* ws  = (float*)d_ws;
    float* dis = ws;                            // N floats (deg -> rsqrt(deg))
    float* h   = ws + (1 << 17);                // N*128 (pre-agg transform)
    float* x1  = h  + (size_t)n * 128;          // N*128 (agg1 -> relu'd x1)
    float* t2  = x1 + (size_t)n * 128;          // N*128 (agg2 -> relu'd x2)

    // zero both aggregators (contiguous)
    hipMemsetAsync(x1, 0, (size_t)n * 128 * 2 * sizeof(float), stream);

    set_ones<<<(n + 255) / 256, 256, 0, stream>>>(dis, n);
    deg_count<<<(E + 255) / 256, 256, 0, stream>>>(dst, dis, E);
    to_rsqrt<<<(n + 255) / 256, 256, 0, stream>>>(dis, n);

    // layer 1
    gemm128<<<(n + 63) / 64, 256, 0, stream>>>(x, W1, h, n, 256);
    {
        long long tot = (long long)E * 128;
        scatter<<<(unsigned)((tot + 255) / 256), 256, 0, stream>>>(h, src, dst, dis, x1, E);
    }
    {
        long long tot = (long long)n * 128;
        bias_relu_self<<<(unsigned)((tot + 255) / 256), 256, 0, stream>>>(x1, h, dis, b1, n);
    }

    // layer 2
    gemm128<<<(n + 63) / 64, 256, 0, stream>>>(x1, W2, h, n, 128);
    {
        long long tot = (long long)E * 128;
        scatter<<<(unsigned)((tot + 255) / 256), 256, 0, stream>>>(h, src, dst, dis, t2, E);
    }
    {
        long long tot = (long long)n * 128;
        bias_relu_self<<<(unsigned)((tot + 255) / 256), 256, 0, stream>>>(t2, h, dis, b2, n);
    }

    // JK head + log_softmax
    final_k<<<(n + 3) / 4, 256, 0, stream>>>(x1, t2, lw, lb, out, n);
}

// Round 2
// 851.009 us; speedup vs baseline: 3.8247x; 3.8247x over previous
//
#include <hip/hip_runtime.h>
#include <math.h>

// ---------------------------------------------------------------------------
// JKNet: 2-layer GCN (sym-norm A+I) + sum-JK + linear + log_softmax. All fp32.
// Round 2: register-blocked fp32 GEMM + device-built CSR gather (no fp atomics).
// ---------------------------------------------------------------------------

#define NPAD (1 << 17)   // padded node-array stride (N=100000)
#define CHUNK 1024       // scan chunk (elements per block)

// ---- CSR build ------------------------------------------------------------

__global__ void hist_kernel(const int* __restrict__ dst, int* __restrict__ cnt, int E) {
    int e = blockIdx.x * 256 + threadIdx.x;
    if (e < E) atomicAdd(&cnt[dst[e]], 1);
}

// per-chunk sums
__global__ void scan_partial(const int* __restrict__ cnt, int* __restrict__ partial, int n) {
    __shared__ int sdata[4];
    int b = blockIdx.x, t = threadIdx.x;
    int base = b * CHUNK;
    int sum = 0;
    for (int i = t; i < CHUNK; i += 256) {
        int idx = base + i;
        if (idx < n) sum += cnt[idx];
    }
#pragma unroll
    for (int off = 32; off > 0; off >>= 1) sum += __shfl_down(sum, off, 64);
    if ((t & 63) == 0) sdata[t >> 6] = sum;
    __syncthreads();
    if (t == 0) partial[b] = sdata[0] + sdata[1] + sdata[2] + sdata[3];
}

// serial exclusive scan of the (small) partial array
__global__ void scan_small(int* partial, int nblk) {
    if (threadIdx.x == 0 && blockIdx.x == 0) {
        int acc = 0;
        for (int i = 0; i < nblk; i++) { int v = partial[i]; partial[i] = acc; acc += v; }
    }
}

// exclusive scan within each chunk + chunk offset; also emit cursor copy and dis
__global__ void scan_final(const int* __restrict__ cnt, const int* __restrict__ partial,
                           int* __restrict__ offs, int* __restrict__ cursor,
                           float* __restrict__ dis, int n) {
    __shared__ int wsum[4];
    int b = blockIdx.x, t = threadIdx.x;
    int lane = t & 63, w = t >> 6;
    int base = b * CHUNK + t * 4;
    int v[4];
#pragma unroll
    for (int j = 0; j < 4; j++) v[j] = (base + j < n) ? cnt[base + j] : 0;
    int s4 = v[0] + v[1] + v[2] + v[3];
    int inc = s4;
#pragma unroll
    for (int off = 1; off < 64; off <<= 1) {
        int x = __shfl_up(inc, off, 64);
        if (lane >= off) inc += x;
    }
    if (lane == 63) wsum[w] = inc;
    __syncthreads();
    int woff = 0;
    for (int i = 0; i < 4; i++) if (i < w) woff += wsum[i];
    int pos = partial[b] + woff + (inc - s4);
#pragma unroll
    for (int j = 0; j < 4; j++) {
        int idx = base + j;
        if (idx < n) {
            offs[idx] = pos;
            cursor[idx] = pos;
            dis[idx] = rsqrtf((float)(v[j] + 1));  // deg = incoming + self-loop
            pos += v[j];
        }
    }
}

__global__ void permute_kernel(const int* __restrict__ src, const int* __restrict__ dst,
                               int* __restrict__ cursor, int* __restrict__ ssrc, int E) {
    int e = blockIdx.x * 256 + threadIdx.x;
    if (e < E) {
        int d = dst[e];
        int pos = atomicAdd(&cursor[d], 1);
        ssrc[pos] = src[e];
    }
}

// ---- GEMM: H[n,128] = X[n,K] @ W[K,128], fp32 register-blocked ------------
// 128x128 tile per block, BK=8, 256 threads, 8x8 per thread.
__global__ __launch_bounds__(256) void gemm_f32(const float* __restrict__ X,
                                                const float* __restrict__ W,
                                                float* __restrict__ H, int n, int K) {
    __shared__ float xs[8][128];   // transposed X tile: xs[k][row]
    __shared__ float wsh[8][128];  // W tile: wsh[k][col]
    int tid = threadIdx.x;
    int row0 = blockIdx.x * 128;
    int tr = tid >> 4, tc = tid & 15;   // 16x16 thread grid
    int lxr = tid >> 1, lxc = (tid & 1) * 4;  // X loader: row, k-offset
    int lwr = tid >> 5, lwc = (tid & 31) * 4; // W loader: k-row, col

    float acc[8][8];
#pragma unroll
    for (int i = 0; i < 8; i++)
#pragma unroll
        for (int j = 0; j < 8; j++) acc[i][j] = 0.f;

    for (int kt = 0; kt < K; kt += 8) {
        int gr = row0 + lxr; if (gr >= n) gr = n - 1;  // clamped rows feed dead outputs only
        float4 xv = *(const float4*)(X + (size_t)gr * K + kt + lxc);
        float4 wv = *(const float4*)(W + (size_t)(kt + lwr) * 128 + lwc);
        xs[lxc + 0][lxr] = xv.x; xs[lxc + 1][lxr] = xv.y;
        xs[lxc + 2][lxr] = xv.z; xs[lxc + 3][lxr] = xv.w;
        *(float4*)&wsh[lwr][lwc] = wv;
        __syncthreads();
#pragma unroll
        for (int k = 0; k < 8; k++) {
            float a[8], bb[8];
            *(float4*)&a[0]  = *(const float4*)&xs[k][tr * 8];
            *(float4*)&a[4]  = *(const float4*)&xs[k][tr * 8 + 4];
            *(float4*)&bb[0] = *(const float4*)&wsh[k][tc * 8];
            *(float4*)&bb[4] = *(const float4*)&wsh[k][tc * 8 + 4];
#pragma unroll
            for (int i = 0; i < 8; i++)
#pragma unroll
                for (int j = 0; j < 8; j++) acc[i][j] = fmaf(a[i], bb[j], acc[i][j]);
        }
        __syncthreads();
    }
#pragma unroll
    for (int i = 0; i < 8; i++) {
        int r = row0 + tr * 8 + i;
        if (r < n) {
            float4* o = (float4*)(H + (size_t)r * 128 + tc * 8);
            o[0] = make_float4(acc[i][0], acc[i][1], acc[i][2], acc[i][3]);
            o[1] = make_float4(acc[i][4], acc[i][5], acc[i][6], acc[i][7]);
        }
    }
}

// ---- CSR gather-aggregate: out[d] = relu(sum_{s in N(d)} h[s]*dis[s]*dis[d]
//                                          + h[d]*dis[d]^2 + b)
// One wave per destination node; 2 features per lane.
__global__ void gather_kernel(const float* __restrict__ H, const int* __restrict__ ssrc,
                              const int* __restrict__ offs, const int* __restrict__ cnt,
                              const float* __restrict__ dis, const float* __restrict__ bias,
                              float* __restrict__ out, int n) {
    int w = threadIdx.x >> 6, lane = threadIdx.x & 63;
    int node = blockIdx.x * 4 + w;
    if (node >= n) return;
    int start = offs[node], c = cnt[node];
    float dd = dis[node];
    float a0 = 0.f, a1 = 0.f;
    int j = 0;
    for (; j + 1 < c; j += 2) {
        int s0 = ssrc[start + j], s1 = ssrc[start + j + 1];
        float n0 = dis[s0] * dd, n1 = dis[s1] * dd;
        const float* h0 = H + (size_t)s0 * 128;
        const float* h1 = H + (size_t)s1 * 128;
        a0 = fmaf(h0[lane],      n0, a0);
        a1 = fmaf(h0[lane + 64], n0, a1);
        a0 = fmaf(h1[lane],      n1, a0);
        a1 = fmaf(h1[lane + 64], n1, a1);
    }
    if (j < c) {
        int s0 = ssrc[start + j];
        float n0 = dis[s0] * dd;
        const float* h0 = H + (size_t)s0 * 128;
        a0 = fmaf(h0[lane],      n0, a0);
        a1 = fmaf(h0[lane + 64], n0, a1);
    }
    const float* hn = H + (size_t)node * 128;
    float sn = dd * dd;
    a0 = fmaf(hn[lane],      sn, a0) + bias[lane];
    a1 = fmaf(hn[lane + 64], sn, a1) + bias[lane + 64];
    out[(size_t)node * 128 + lane]      = a0 > 0.f ? a0 : 0.f;
    out[(size_t)node * 128 + 64 + lane] = a1 > 0.f ? a1 : 0.f;
}

// ---- JK head: out[node,0:41] = log_softmax((x1+x2) @ lw + lb) -------------
__global__ void final_k(const float* __restrict__ x1, const float* __restrict__ x2,
                        const float* __restrict__ lw, const float* __restrict__ lb,
                        float* __restrict__ out, int n) {
    __shared__ float s[4][128];
    int g = threadIdx.x >> 6, lane = threadIdx.x & 63;
    int node = blockIdx.x * 4 + g;
    if (node < n) {
        size_t base = (size_t)node * 128;
        s[g][lane]      = x1[base + lane]      + x2[base + lane];
        s[g][lane + 64] = x1[base + lane + 64] + x2[base + lane + 64];
    }
    __syncthreads();
    bool active = (node < n) && (lane < 41);
    float val = 0.f;
    if (active) {
#pragma unroll 4
        for (int f = 0; f < 128; f++) val = fmaf(s[g][f], lw[f * 41 + lane], val);
        val += lb[lane];
    }
    float m = active ? val : -INFINITY;
#pragma unroll
    for (int off = 32; off > 0; off >>= 1) m = fmaxf(m, __shfl_xor(m, off, 64));
    float e = active ? expf(val - m) : 0.f;
#pragma unroll
    for (int off = 32; off > 0; off >>= 1) e += __shfl_xor(e, off, 64);
    if (active) out[(size_t)node * 41 + lane] = val - m - logf(e);
}

extern "C" void kernel_launch(void* const* d_in, const int* in_sizes, int n_in,
                              void* d_out, int out_size, void* d_ws, size_t ws_size,
                              hipStream_t stream) {
    const float* x  = (const float*)d_in[0];
    const int*   ei = (const int*)d_in[1];
    const float* W1 = (const float*)d_in[2];
    const float* b1 = (const float*)d_in[3];
    const float* W2 = (const float*)d_in[4];
    const float* b2 = (const float*)d_in[5];
    const float* lw = (const float*)d_in[6];
    const float* lb = (const float*)d_in[7];
    float* out = (float*)d_out;

    const int n = in_sizes[0] / 256;   // 100000
    const int E = in_sizes[1] / 2;     // 1600000
    const int* src = ei;
    const int* dst = ei + E;

    // workspace layout
    int*   cnt    = (int*)d_ws;                    // NPAD
    int*   offs   = cnt + NPAD;                    // NPAD
    int*   cursor = offs + NPAD;                   // NPAD
    int*   partial= cursor + NPAD;                 // small (scan partials)
    float* dis    = (float*)(partial + 1024);      // NPAD
    int*   ssrc   = (int*)(dis + NPAD);            // E (rounded up)
    size_t Epad   = ((size_t)E + 255) & ~(size_t)255;
    float* h      = (float*)(ssrc + Epad);         // N*128
    float* x1     = h  + (size_t)n * 128;          // N*128
    float* t2     = x1 + (size_t)n * 128;          // N*128

    const int nscan = (n + CHUNK - 1) / CHUNK;

    // ---- CSR build (once, reused by both layers) ----
    hipMemsetAsync(cnt, 0, (size_t)n * sizeof(int), stream);
    hist_kernel<<<(E + 255) / 256, 256, 0, stream>>>(dst, cnt, E);
    scan_partial<<<nscan, 256, 0, stream>>>(cnt, partial, n);
    scan_small<<<1, 64, 0, stream>>>(partial, nscan);
    scan_final<<<nscan, 256, 0, stream>>>(cnt, partial, offs, cursor, dis, n);
    permute_kernel<<<(E + 255) / 256, 256, 0, stream>>>(src, dst, cursor, ssrc, E);

    // ---- layer 1 ----
    gemm_f32<<<(n + 127) / 128, 256, 0, stream>>>(x, W1, h, n, 256);
    gather_kernel<<<(n + 3) / 4, 256, 0, stream>>>(h, ssrc, offs, cnt, dis, b1, x1, n);

    // ---- layer 2 ----
    gemm_f32<<<(n + 127) / 128, 256, 0, stream>>>(x1, W2, h, n, 128);
    gather_kernel<<<(n + 3) / 4, 256, 0, stream>>>(h, ssrc, offs, cnt, dis, b2, t2, n);

    // ---- JK head ----
    final_k<<<(n + 3) / 4, 256, 0, stream>>>(x1, t2, lw, lb, out, n);
}

// Round 3
// 649.527 us; speedup vs baseline: 5.0111x; 1.3102x over previous
//
#include <hip/hip_runtime.h>
#include <math.h>

// ---------------------------------------------------------------------------
// JKNet: 2-layer GCN (sym-norm A+I) + sum-JK + linear + log_softmax.
// Round 3: bf16 MFMA GEMMs, bf16 h/x1 (halves gather fetch), bucketed
// counting-sort permute (kills scatter write-amp), head fused into gather2.
// ---------------------------------------------------------------------------

#define NPAD (1 << 17)   // padded node-array stride (N=100000)
#define CHUNK 1024       // scan chunk (elements per block)

typedef __attribute__((ext_vector_type(8))) short short8;
typedef __attribute__((ext_vector_type(4))) float f32x4;

__device__ inline unsigned short f2bf(float f) {
    unsigned u = __builtin_bit_cast(unsigned, f);
    return (unsigned short)((u + 0x7fffu + ((u >> 16) & 1u)) >> 16);
}
__device__ inline float bflo(unsigned u) { return __builtin_bit_cast(float, u << 16); }
__device__ inline float bfhi(unsigned u) { return __builtin_bit_cast(float, u & 0xffff0000u); }

// ---- CSR build ------------------------------------------------------------

__global__ void hist_kernel(const int* __restrict__ dst, int* __restrict__ cnt, int E) {
    int e = blockIdx.x * 256 + threadIdx.x;
    if (e < E) atomicAdd(&cnt[dst[e]], 1);
}

__global__ void scan_partial(const int* __restrict__ cnt, int* __restrict__ partial, int n) {
    __shared__ int sdata[4];
    int b = blockIdx.x, t = threadIdx.x;
    int base = b * CHUNK;
    int sum = 0;
    for (int i = t; i < CHUNK; i += 256) {
        int idx = base + i;
        if (idx < n) sum += cnt[idx];
    }
#pragma unroll
    for (int off = 32; off > 0; off >>= 1) sum += __shfl_down(sum, off, 64);
    if ((t & 63) == 0) sdata[t >> 6] = sum;
    __syncthreads();
    if (t == 0) partial[b] = sdata[0] + sdata[1] + sdata[2] + sdata[3];
}

__global__ void scan_small(int* partial, int nblk) {
    if (threadIdx.x == 0 && blockIdx.x == 0) {
        int acc = 0;
        for (int i = 0; i < nblk; i++) { int v = partial[i]; partial[i] = acc; acc += v; }
    }
}

__global__ void scan_final(const int* __restrict__ cnt, const int* __restrict__ partial,
                           int* __restrict__ offs, int* __restrict__ cursor,
                           float* __restrict__ dis, int n) {
    __shared__ int wsum[4];
    int b = blockIdx.x, t = threadIdx.x;
    int lane = t & 63, w = t >> 6;
    int base = b * CHUNK + t * 4;
    int v[4];
#pragma unroll
    for (int j = 0; j < 4; j++) v[j] = (base + j < n) ? cnt[base + j] : 0;
    int s4 = v[0] + v[1] + v[2] + v[3];
    int inc = s4;
#pragma unroll
    for (int off = 1; off < 64; off <<= 1) {
        int x = __shfl_up(inc, off, 64);
        if (lane >= off) inc += x;
    }
    if (lane == 63) wsum[w] = inc;
    __syncthreads();
    int woff = 0;
    for (int i = 0; i < 4; i++) if (i < w) woff += wsum[i];
    int pos = partial[b] + woff + (inc - s4);
#pragma unroll
    for (int j = 0; j < 4; j++) {
        int idx = base + j;
        if (idx < n) {
            offs[idx] = pos;
            cursor[idx] = pos;
            dis[idx] = rsqrtf((float)(v[j] + 1));  // deg = incoming + self-loop
            pos += v[j];
        }
    }
}

// Bucketed permute: only edges with dst in [lo,hi) — keeps cursor atomics and
// ssrc scatter writes inside an L2-resident window.
__global__ void permute_bucket(const int* __restrict__ src, const int* __restrict__ dst,
                               int* __restrict__ cursor, int* __restrict__ ssrc,
                               int E, int lo, int hi) {
    int e = blockIdx.x * 256 + threadIdx.x;
    if (e < E) {
        int d = dst[e];
        if (d >= lo && d < hi) {
            int pos = atomicAdd(&cursor[d], 1);
            ssrc[pos] = src[e];
        }
    }
}

// ---- W cast+transpose: Wt[n][k] = bf16(W[k][n]) ---------------------------
__global__ void wcast(const float* __restrict__ W, unsigned short* __restrict__ Wt, int K) {
    int i = blockIdx.x * 256 + threadIdx.x;
    if (i < K * 128) {
        int k = i >> 7, nn = i & 127;
        Wt[nn * K + k] = f2bf(W[i]);
    }
}

// ---- MFMA GEMM: Hb[n,128](bf16) = A[n,K] @ W[K,128] -----------------------
// Block: 256 thr = 4 waves, 64 rows/block, full 128 cols. B (Wt, [128][K] bf16)
// staged in LDS per 128-K chunk; A-frags straight from global.
template<bool ABF16>
__global__ __launch_bounds__(256) void gemm_mfma(const void* __restrict__ Ap,
                                                 const unsigned short* __restrict__ Wt,
                                                 unsigned short* __restrict__ Hb,
                                                 int n, int K) {
    __shared__ unsigned short bs[128 * 136];   // rows padded to 136 (2-way free)
    const int tid = threadIdx.x;
    const int wave = tid >> 6, lane = tid & 63;
    const int quad = lane >> 4, mrow = lane & 15;
    const int arow_g = blockIdx.x * 64 + wave * 16 + mrow;
    const int arow = arow_g < n ? arow_g : n - 1;

    f32x4 acc[8];
#pragma unroll
    for (int t = 0; t < 8; t++) acc[t] = (f32x4){0.f, 0.f, 0.f, 0.f};

    const float* Af = (const float*)Ap;
    const unsigned short* Ab = (const unsigned short*)Ap;

    for (int kc = 0; kc < K; kc += 128) {
        __syncthreads();
        for (int i = tid; i < 2048; i += 256) {      // 128 rows x 16 chunks of 8
            int row = i >> 4, c8 = i & 15;
            *(short8*)&bs[row * 136 + c8 * 8] = *(const short8*)&Wt[row * K + kc + c8 * 8];
        }
        __syncthreads();
#pragma unroll
        for (int kt = 0; kt < 128; kt += 32) {
            union { short8 v; unsigned short u[8]; } A;
            if (ABF16) {
                A.v = *(const short8*)&Ab[(size_t)arow * K + kc + kt + quad * 8];
            } else {
                const float* ap = &Af[(size_t)arow * K + kc + kt + quad * 8];
                float4 p0 = *(const float4*)ap;
                float4 p1 = *(const float4*)(ap + 4);
                A.u[0] = f2bf(p0.x); A.u[1] = f2bf(p0.y);
                A.u[2] = f2bf(p0.z); A.u[3] = f2bf(p0.w);
                A.u[4] = f2bf(p1.x); A.u[5] = f2bf(p1.y);
                A.u[6] = f2bf(p1.z); A.u[7] = f2bf(p1.w);
            }
#pragma unroll
            for (int nt = 0; nt < 8; nt++) {
                short8 B = *(const short8*)&bs[(nt * 16 + mrow) * 136 + kt + quad * 8];
                acc[nt] = __builtin_amdgcn_mfma_f32_16x16x32_bf16(A.v, B, acc[nt], 0, 0, 0);
            }
        }
    }
    // D layout: col = lane&15 (+nt*16), row = quad*4 + r (+wave*16)
    const int drow0 = blockIdx.x * 64 + wave * 16 + quad * 4;
#pragma unroll
    for (int r = 0; r < 4; r++) {
        int dr = drow0 + r;
        if (dr < n) {
#pragma unroll
            for (int nt = 0; nt < 8; nt++)
                Hb[(size_t)dr * 128 + nt * 16 + mrow] = f2bf(acc[nt][r]);
        }
    }
}

// ---- CSR gather (+optional fused JK head) ---------------------------------
// One wave per dst node; lane owns feature pair (2l, 2l+1). Hb is bf16.
template<bool FUSE>
__global__ __launch_bounds__(256) void gather_k(const unsigned short* __restrict__ Hb,
                                                const int* __restrict__ ssrc,
                                                const int* __restrict__ offs,
                                                const int* __restrict__ cnt,
                                                const float* __restrict__ dis,
                                                const float* __restrict__ bias,
                                                unsigned short* __restrict__ outb,
                                                const unsigned short* __restrict__ x1b,
                                                const float* __restrict__ lw,
                                                const float* __restrict__ lb,
                                                float* __restrict__ out, int n) {
    __shared__ float s[4][128];
    int w = threadIdx.x >> 6, lane = threadIdx.x & 63;
    int node = blockIdx.x * 4 + w;
    bool valid = node < n;
    int nd = valid ? node : n - 1;
    int start = offs[nd], c = cnt[nd];
    float dd = dis[nd];
    const unsigned* Hu = (const unsigned*)Hb;
    float a0 = 0.f, a1 = 0.f;
    int j = 0;
    for (; j + 3 < c; j += 4) {
        int s0 = ssrc[start + j],     s1 = ssrc[start + j + 1];
        int s2 = ssrc[start + j + 2], s3 = ssrc[start + j + 3];
        unsigned u0 = Hu[(size_t)s0 * 64 + lane], u1 = Hu[(size_t)s1 * 64 + lane];
        unsigned u2 = Hu[(size_t)s2 * 64 + lane], u3 = Hu[(size_t)s3 * 64 + lane];
        float n0 = dis[s0] * dd, n1 = dis[s1] * dd;
        float n2 = dis[s2] * dd, n3 = dis[s3] * dd;
        a0 = fmaf(bflo(u0), n0, a0); a1 = fmaf(bfhi(u0), n0, a1);
        a0 = fmaf(bflo(u1), n1, a0); a1 = fmaf(bfhi(u1), n1, a1);
        a0 = fmaf(bflo(u2), n2, a0); a1 = fmaf(bfhi(u2), n2, a1);
        a0 = fmaf(bflo(u3), n3, a0); a1 = fmaf(bfhi(u3), n3, a1);
    }
    for (; j < c; j++) {
        int s0 = ssrc[start + j];
        unsigned u0 = Hu[(size_t)s0 * 64 + lane];
        float n0 = dis[s0] * dd;
        a0 = fmaf(bflo(u0), n0, a0); a1 = fmaf(bfhi(u0), n0, a1);
    }
    // self-loop + bias + relu
    unsigned us = Hu[(size_t)nd * 64 + lane];
    float sn = dd * dd;
    float2 bb = ((const float2*)bias)[lane];
    a0 = fmaf(bflo(us), sn, a0) + bb.x;
    a1 = fmaf(bfhi(us), sn, a1) + bb.y;
    a0 = a0 > 0.f ? a0 : 0.f;
    a1 = a1 > 0.f ? a1 : 0.f;

    if (!FUSE) {
        if (valid) {
            unsigned pk = ((unsigned)f2bf(a1) << 16) | (unsigned)f2bf(a0);
            ((unsigned*)outb)[(size_t)node * 64 + lane] = pk;
        }
    } else {
        unsigned xu = ((const unsigned*)x1b)[(size_t)nd * 64 + lane];
        s[w][2 * lane]     = a0 + bflo(xu);
        s[w][2 * lane + 1] = a1 + bfhi(xu);
        __syncthreads();
        bool act = valid && (lane < 41);
        float val = 0.f;
        if (act) {
#pragma unroll 4
            for (int f = 0; f < 128; f++) val = fmaf(s[w][f], lw[f * 41 + lane], val);
            val += lb[lane];
        }
        float m = act ? val : -INFINITY;
#pragma unroll
        for (int off = 32; off > 0; off >>= 1) m = fmaxf(m, __shfl_xor(m, off, 64));
        float e = act ? expf(val - m) : 0.f;
#pragma unroll
        for (int off = 32; off > 0; off >>= 1) e += __shfl_xor(e, off, 64);
        if (act) out[(size_t)node * 41 + lane] = val - m - logf(e);
    }
}

extern "C" void kernel_launch(void* const* d_in, const int* in_sizes, int n_in,
                              void* d_out, int out_size, void* d_ws, size_t ws_size,
                              hipStream_t stream) {
    const float* x  = (const float*)d_in[0];
    const int*   ei = (const int*)d_in[1];
    const float* W1 = (const float*)d_in[2];
    const float* b1 = (const float*)d_in[3];
    const float* W2 = (const float*)d_in[4];
    const float* b2 = (const float*)d_in[5];
    const float* lw = (const float*)d_in[6];
    const float* lb = (const float*)d_in[7];
    float* out = (float*)d_out;

    const int n = in_sizes[0] / 256;   // 100000
    const int E = in_sizes[1] / 2;     // 1600000
    const int* src = ei;
    const int* dst = ei + E;

    // workspace layout
    int*   cnt     = (int*)d_ws;                       // NPAD
    int*   offs    = cnt + NPAD;                       // NPAD
    int*   cursor  = offs + NPAD;                      // NPAD
    int*   partial = cursor + NPAD;                    // 1024
    float* dis     = (float*)(partial + 1024);         // NPAD
    int*   ssrc    = (int*)(dis + NPAD);               // Epad
    size_t Epad    = ((size_t)E + 255) & ~(size_t)255;
    unsigned short* Wt1 = (unsigned short*)(ssrc + Epad);  // 256*128 bf16
    unsigned short* Wt2 = Wt1 + 256 * 128;                 // 128*128 bf16
    unsigned short* Hb  = Wt2 + 128 * 128;                 // n*128 bf16
    unsigned short* X1b = Hb + (size_t)n * 128;            // n*128 bf16

    const int nscan = (n + CHUNK - 1) / CHUNK;

    hipMemsetAsync(cnt, 0, (size_t)n * sizeof(int), stream);
    wcast<<<(256 * 128 + 255) / 256, 256, 0, stream>>>(W1, Wt1, 256);
    wcast<<<(128 * 128 + 255) / 256, 256, 0, stream>>>(W2, Wt2, 128);

    // CSR build (reused by both layers)
    hist_kernel<<<(E + 255) / 256, 256, 0, stream>>>(dst, cnt, E);
    scan_partial<<<nscan, 256, 0, stream>>>(cnt, partial, n);
    scan_small<<<1, 64, 0, stream>>>(partial, nscan);
    scan_final<<<nscan, 256, 0, stream>>>(cnt, partial, offs, cursor, dis, n);
    {
        const int NBUCKET = 4;
        int W = (n + NBUCKET - 1) / NBUCKET;
        for (int p = 0; p < NBUCKET; p++) {
            int lo = p * W, hi = lo + W < n ? lo + W : n;
            permute_bucket<<<(E + 255) / 256, 256, 0, stream>>>(src, dst, cursor, ssrc, E, lo, hi);
        }
    }

    // layer 1: h = bf16(x @ W1); x1 = relu(agg) (bf16)
    gemm_mfma<false><<<(n + 63) / 64, 256, 0, stream>>>(x, Wt1, Hb, n, 256);
    gather_k<false><<<(n + 3) / 4, 256, 0, stream>>>(Hb, ssrc, offs, cnt, dis, b1, X1b,
                                                     nullptr, nullptr, nullptr, nullptr, n);

    // layer 2 + fused JK head
    gemm_mfma<true><<<(n + 63) / 64, 256, 0, stream>>>(X1b, Wt2, Hb, n, 128);
    gather_k<true><<<(n + 3) / 4, 256, 0, stream>>>(Hb, ssrc, offs, cnt, dis, b2, nullptr,
                                                    X1b, lw, lb, out, n);
}